// Round 2
// baseline (657.070 us; speedup 1.0000x reference)
//
#include <hip/hip_runtime.h>
#include <stdint.h>

#define NP    676
#define NPAD  768
#define DD    384
#define MM    200000
#define IMG   224

typedef unsigned int u32;
typedef unsigned long long u64;
typedef short bf16x8 __attribute__((ext_vector_type(8)));
typedef float f32x4 __attribute__((ext_vector_type(4)));

// ---- workspace layout (bytes) ----
#define WS_PACKED   0u         // u64[768]   max-dot keys per row
#define WS_SCAL     6144u      // u32 s_idx, u32 j_star, f32 s_star
#define WS_MV       6400u      // f32[768]   min_val per row
#define WS_TOPS     9728u      // u64[128*5] per-block top5 of d_star
#define WS_PNORM    15360u     // f32[768*384] normalized patch
#define WS_PNB      1195008u   // ushort[768*384] bf16 normalized patch
#define WS_DSTAR    1784832u   // u64[200000] packed (dist,idx)
#define WS_BUFA     3384832u   // f32[50176] resized map
#define WS_BUFB     3585536u   // f32[50176] h-blurred map
#define WS_LIBH     3786240u   // ushort[200000*384] bf16 lib (153.6 MB)

__device__ inline unsigned short f2bf(float f) {
  u32 u = __float_as_uint(f);
  u += 0x7FFFu + ((u >> 16) & 1u);
  return (unsigned short)(u >> 16);
}
__device__ inline float bflo(u32 u) { return __uint_as_float(u << 16); }
__device__ inline float bfhi(u32 u) { return __uint_as_float(u & 0xFFFF0000u); }

// async global->LDS, 16 B per lane: per-lane global src, wave-uniform LDS dst + lane*16
__device__ __forceinline__ void gld16(const void* g, void* l) {
  __builtin_amdgcn_global_load_lds((const __attribute__((address_space(1))) u32*)g,
                                   (__attribute__((address_space(3))) u32*)l, 16, 0, 0);
}

// ---- K1: L2-normalize patch rows, write fp32 + bf16, pad rows to 768.
// Also zero-inits packed_[768] (fused former k_init; blocks 0..5 cover it).
__global__ void k_norm(const float* __restrict__ patch, float* __restrict__ pnorm,
                       unsigned short* __restrict__ pnb, u64* __restrict__ packed_) {
  __shared__ float red[2];
  __shared__ float scs;
  int i = blockIdx.x, t = threadIdx.x;
  if (i < 6) packed_[i * 128 + t] = 0ull;
  if (i >= NP) {
    for (int j = 0; j < 3; ++j) {
      pnorm[(size_t)i * DD + t + 128 * j] = 0.f;
      pnb[(size_t)i * DD + t + 128 * j] = 0;
    }
    return;
  }
  float x0 = patch[(size_t)i * DD + t];
  float x1 = patch[(size_t)i * DD + t + 128];
  float x2 = patch[(size_t)i * DD + t + 256];
  float s = x0 * x0 + x1 * x1 + x2 * x2;
#pragma unroll
  for (int m = 1; m < 64; m <<= 1) s += __shfl_xor(s, m, 64);
  if ((t & 63) == 0) red[t >> 6] = s;
  __syncthreads();
  if (t == 0) scs = 1.f / fmaxf(sqrtf(red[0] + red[1]), 1e-12f);
  __syncthreads();
  float k = scs;
  pnorm[(size_t)i * DD + t]       = x0 * k;
  pnorm[(size_t)i * DD + t + 128] = x1 * k;
  pnorm[(size_t)i * DD + t + 256] = x2 * k;
  pnb[(size_t)i * DD + t]       = f2bf(x0 * k);
  pnb[(size_t)i * DD + t + 128] = f2bf(x1 * k);
  pnb[(size_t)i * DD + t + 256] = f2bf(x2 * k);
}

// ---- K1b: one-time lib fp32 -> bf16 (bf16 lib fits in L3) ----
__global__ void k_conv(const float* __restrict__ lib, unsigned short* __restrict__ libh) {
  const size_t n4 = (size_t)MM * DD / 8;   // output uint4 units (8 bf16)
  const size_t stride = (size_t)gridDim.x * 256;
  const float4* src = (const float4*)lib;
  uint4* dst = (uint4*)libh;
  for (size_t i = (size_t)blockIdx.x * 256 + threadIdx.x; i < n4; i += stride) {
    float4 f0 = src[2 * i], f1 = src[2 * i + 1];
    uint4 o;
    o.x = (u32)f2bf(f0.x) | ((u32)f2bf(f0.y) << 16);
    o.y = (u32)f2bf(f0.z) | ((u32)f2bf(f0.w) << 16);
    o.z = (u32)f2bf(f1.x) | ((u32)f2bf(f1.y) << 16);
    o.w = (u32)f2bf(f1.z) | ((u32)f2bf(f1.w) << 16);
    dst[i] = o;
  }
}

// ---- K2: main pass. 782 col-chunks x 3 row-groups; bijective XCD swizzle puts the
// 3 row-groups of a col-panel on ONE XCD (panel fetched once per XCD, L2-served 3x).
// A fragments register-resident. __launch_bounds__(256,1): 512-reg/wave budget so the
// ~300-reg working set (192 A-frag + acc + addressing) does NOT spill to scratch
// (with (256,2) the compiler spilled areg -> ~7.2 GB/launch scratch traffic).
// B streamed via global_load_lds into 4 LDS buffers of 16 cols, depth-3 in flight,
// counted vmcnt(6) + raw s_barrier (no drains).
// Fold: biased-float key (dot+3 > 0 so raw bits are monotonic) -> 4 VALU/acc.
__global__ __launch_bounds__(256, 1) void k_pass1(const unsigned short* __restrict__ pnb,
                                                  const unsigned short* __restrict__ libh,
                                                  u64* __restrict__ packed_) {
  __shared__ __align__(16) unsigned short bt[4 * 6144];   // 4 bufs x 12288 B = 49152 B
  const int t = threadIdx.x;
  // bijective XCD swizzle: 2346 = 8*293 + 2
  const int xcd = blockIdx.x & 7;
  const int idx = blockIdx.x >> 3;
  const int logical = xcd * 293 + (xcd < 2 ? xcd : 2) + idx;
  const int cc = logical / 3, rg = logical - cc * 3;
  const int col0 = cc * 256;
  const int rowbase = rg * 256;
  const int wave = t >> 6, lane = t & 63;
  const int quad = lane >> 4, l15 = lane & 15;
  const int nchunk = (MM - col0 < 256) ? (MM - col0) / 16 : 16;

  // per-lane staging source offsets: slot s=(wave*3+it)*64+lane -> (r=s/48, u=s%48),
  // source unit = u ^ (r&7) so linear LDS write realizes the swizzled layout
  u32 soff[3];
#pragma unroll
  for (int it = 0; it < 3; ++it) {
    int slot = (wave * 3 + it) * 64 + lane;
    int r = slot / 48, u = slot - r * 48;
    soff[it] = (u32)(r * 768 + ((u ^ (r & 7)) << 4));
  }
  // per-lane fragment read byte-offsets within a 12288-B tile (row l15, unit quad+4kt)
  int bo[12];
#pragma unroll
  for (int kt = 0; kt < 12; ++kt)
    bo[kt] = l15 * 768 + (((quad + kt * 4) ^ (l15 & 7)) << 4);

  // ---- A prologue: round q stages 16-row pieces (q+4j)->buf j; wave w reads buf w (mi=q)
  bf16x8 areg[4][12];
#pragma unroll
  for (int q = 0; q < 4; ++q) {
    if (q) __syncthreads();                 // prev round's reads done before overwrite
#pragma unroll
    for (int j = 0; j < 4; ++j) {
      const char* srcb = (const char*)pnb + (size_t)(rowbase + (q + 4 * j) * 16) * 768;
#pragma unroll
      for (int it = 0; it < 3; ++it)
        gld16(srcb + soff[it], (char*)bt + j * 12288 + (wave * 3 + it) * 1024);
    }
    __syncthreads();                        // full vmcnt drain -> staged data visible
#pragma unroll
    for (int kt = 0; kt < 12; ++kt)
      areg[q][kt] = *(const bf16x8*)((const char*)bt + wave * 12288 + bo[kt]);
  }
  __syncthreads();                          // all A-frag reads done before B staging

  u32 best[16];
#pragma unroll
  for (int j = 0; j < 16; ++j) best[j] = 0u;

  const char* bsrc = (const char*)libh + (size_t)col0 * 768;
  // pipeline prologue: stage chunks 0..2 into bufs 0..2 (9 gl_lds outstanding per wave)
#pragma unroll
  for (int pc = 0; pc < 3; ++pc) {
#pragma unroll
    for (int it = 0; it < 3; ++it)
      gld16(bsrc + (size_t)pc * 12288 + soff[it],
            (char*)bt + pc * 12288 + (wave * 3 + it) * 1024);
  }

#pragma unroll 1
  for (int c = 0; c < nchunk; ++c) {
    // wait only for chunk c (3 loads/wave/chunk; keep c+1,c+2 in flight)
    if (c + 3 <= nchunk)      asm volatile("s_waitcnt vmcnt(6)" ::: "memory");
    else if (c + 2 == nchunk) asm volatile("s_waitcnt vmcnt(3)" ::: "memory");
    else                      asm volatile("s_waitcnt vmcnt(0)" ::: "memory");
    __builtin_amdgcn_s_barrier();           // also fences buf (c+3)&3 vs compute(c-1)
    __builtin_amdgcn_sched_barrier(0);
    if (c + 3 < nchunk) {
      const int nb = (c + 3) & 3;
#pragma unroll
      for (int it = 0; it < 3; ++it)
        gld16(bsrc + (size_t)(c + 3) * 12288 + soff[it],
              (char*)bt + nb * 12288 + (wave * 3 + it) * 1024);
    }
    const char* bufb = (const char*)bt + (c & 3) * 12288;
    f32x4 acc[4];
#pragma unroll
    for (int mi = 0; mi < 4; ++mi) {
      acc[mi][0] = 0.f; acc[mi][1] = 0.f; acc[mi][2] = 0.f; acc[mi][3] = 0.f;
    }
#pragma unroll
    for (int kt = 0; kt < 12; ++kt) {
      bf16x8 bf = *(const bf16x8*)(bufb + bo[kt]);
#pragma unroll
      for (int mi = 0; mi < 4; ++mi)
        acc[mi] = __builtin_amdgcn_mfma_f32_16x16x32_bf16(areg[mi][kt], bf, acc[mi], 0, 0, 0);
    }
    // fold: biased key = bits(dot+3)[31:8] | (255 - col_in_wg)  (smaller col wins ties)
    const u32 colbits = 255u - (u32)(c * 16 + l15);
#pragma unroll
    for (int mi = 0; mi < 4; ++mi)
#pragma unroll
      for (int r = 0; r < 4; ++r) {
        u32 kb = __float_as_uint(acc[mi][r] + 3.0f);
        u32 k = (kb & 0xFFFFFF00u) | colbits;
        if (k > best[mi * 4 + r]) best[mi * 4 + r] = k;
      }
  }

  // ---- epilogue: butterfly over the 16 col-lanes, then one global atomic/row
#pragma unroll
  for (int mi = 0; mi < 4; ++mi)
#pragma unroll
    for (int r = 0; r < 4; ++r) {
      u32 k = best[mi * 4 + r];
#pragma unroll
      for (int m = 1; m < 16; m <<= 1) {
        u32 o = (u32)__shfl_xor((int)k, m, 64);
        k = o > k ? o : k;
      }
      if (l15 == 0) {
        int col = col0 + 255 - (int)(k & 255u);
        int row = rowbase + wave * 64 + mi * 16 + quad * 4 + r;
        u64 g = ((u64)(k & 0xFFFFFF00u) << 32) | (u64)(0xFFFFFFFFu - (u32)col);
        atomicMax(&packed_[row], g);
      }
    }
}

// ---- K3: min_val[i], s_idx = argmax(min_val) (first-index tie), j_star ----
__global__ void k_select(const u64* __restrict__ packed_, u32* __restrict__ scal,
                         float* __restrict__ mv) {
  __shared__ u64 red[256];
  int t = threadIdx.x;
  u64 best = 0ull;
  for (int i = t; i < NP; i += 256) {
    u64 p = packed_[i];
    float d = __uint_as_float((u32)(p >> 32)) - 3.0f;   // un-bias
    float dist = sqrtf(fmaxf(2.f - 2.f * d, 0.f));
    mv[i] = dist;
    u64 key = ((u64)__float_as_uint(dist) << 32) | (u32)(0xFFFFFFFFu - (u32)i);
    if (key > best) best = key;
  }
  red[t] = best;
  __syncthreads();
  for (int s = 128; s > 0; s >>= 1) {
    if (t < s && red[t + s] > red[t]) red[t] = red[t + s];
    __syncthreads();
  }
  if (t == 0) {
    u64 k = red[0];
    u32 sidx = 0xFFFFFFFFu - (u32)k;
    u64 p = packed_[sidx];
    u32 jstar = 0xFFFFFFFFu - (u32)p;
    scal[0] = sidx;
    scal[1] = jstar;
    ((float*)scal)[2] = __uint_as_float((u32)(k >> 32));
  }
}

// ---- K4: d_star from bf16 lib (selection only); 4 rows/wave via 16-lane groups
__global__ void k_dstar(const unsigned short* __restrict__ libh, const u32* __restrict__ scal,
                        u64* __restrict__ dstar) {
  int gid = blockIdx.x * 256 + threadIdx.x;
  int w = gid >> 6, lane = gid & 63;
  int quad = lane >> 4, l15 = lane & 15;
  u32 jstar = scal[1];
  const uint4* ms = (const uint4*)(libh + (size_t)jstar * DD);   // 48 uint4/row
  float mf[24];
#pragma unroll
  for (int j = 0; j < 3; ++j) {
    uint4 u = ms[j * 16 + l15];
    mf[j * 8 + 0] = bflo(u.x); mf[j * 8 + 1] = bfhi(u.x);
    mf[j * 8 + 2] = bflo(u.y); mf[j * 8 + 3] = bfhi(u.y);
    mf[j * 8 + 4] = bflo(u.z); mf[j * 8 + 5] = bfhi(u.z);
    mf[j * 8 + 6] = bflo(u.w); mf[j * 8 + 7] = bfhi(u.w);
  }
  for (int r4 = w; r4 < 50000; r4 += 3200) {
    int row = r4 * 4 + quad;
    const uint4* xr = (const uint4*)(libh + (size_t)row * DD);
    float dot = 0.f;
#pragma unroll
    for (int j = 0; j < 3; ++j) {
      uint4 u = xr[j * 16 + l15];
      dot += mf[j * 8 + 0] * bflo(u.x) + mf[j * 8 + 1] * bfhi(u.x);
      dot += mf[j * 8 + 2] * bflo(u.y) + mf[j * 8 + 3] * bfhi(u.y);
      dot += mf[j * 8 + 4] * bflo(u.z) + mf[j * 8 + 5] * bfhi(u.z);
      dot += mf[j * 8 + 6] * bflo(u.w) + mf[j * 8 + 7] * bfhi(u.w);
    }
#pragma unroll
    for (int mm = 1; mm < 16; mm <<= 1) dot += __shfl_xor(dot, mm, 64);
    if (l15 == 0) {
      float dist = sqrtf(fmaxf(2.f - 2.f * dot, 0.f));
      dstar[row] = ((u64)__float_as_uint(dist) << 32) | (u32)row;
    }
  }
}

__device__ inline void merge5(const u64* a, const u64* b, u64* o) {
  int ia = 0, ib = 0;
#pragma unroll
  for (int j = 0; j < 5; ++j) {
    u64 va = a[ia], vb = b[ib];
    if (va <= vb) { o[j] = va; ++ia; } else { o[j] = vb; ++ib; }
  }
}

// ---- K5a: per-block top-5 smallest of d_star ----
__global__ void k_top5a(const u64* __restrict__ dstar, u64* __restrict__ tops) {
  __shared__ u64 l[256 * 5];
  int t = threadIdx.x, b = blockIdx.x;
  int start = b * 1563;
  int end = start + 1563; if (end > MM) end = MM;
  u64 a0 = ~0ull, a1 = ~0ull, a2 = ~0ull, a3 = ~0ull, a4 = ~0ull;
  for (int i = start + t; i < end; i += 256) {
    u64 v = dstar[i];
    if (v < a4) {
      if (v < a0)      { a4 = a3; a3 = a2; a2 = a1; a1 = a0; a0 = v; }
      else if (v < a1) { a4 = a3; a3 = a2; a2 = a1; a1 = v; }
      else if (v < a2) { a4 = a3; a3 = a2; a2 = v; }
      else if (v < a3) { a4 = a3; a3 = v; }
      else             { a4 = v; }
    }
  }
  l[t * 5 + 0] = a0; l[t * 5 + 1] = a1; l[t * 5 + 2] = a2; l[t * 5 + 3] = a3; l[t * 5 + 4] = a4;
  __syncthreads();
  for (int s = 128; s > 0; s >>= 1) {
    if (t < s) {
      u64 o[5];
      merge5(&l[t * 5], &l[(t + s) * 5], o);
#pragma unroll
      for (int j = 0; j < 5; ++j) l[t * 5 + j] = o[j];
    }
    __syncthreads();
  }
  if (t < 5) tops[b * 5 + t] = l[t];
}

// ---- K5b: global top-5 merge + final scalar s (exact fp32 via lib/pnorm) ----
__global__ void k_final(const u64* __restrict__ tops, const u32* __restrict__ scal,
                        const float* __restrict__ pnorm, const float* __restrict__ lib,
                        float* __restrict__ out) {
  __shared__ u64 l[128 * 5];
  __shared__ u32 nn[5];
  int t = threadIdx.x;
  if (t < 128) {
#pragma unroll
    for (int j = 0; j < 5; ++j) l[t * 5 + j] = tops[t * 5 + j];
  }
  __syncthreads();
  for (int s = 64; s > 0; s >>= 1) {
    if (t < s) {
      u64 o[5];
      merge5(&l[t * 5], &l[(t + s) * 5], o);
#pragma unroll
      for (int j = 0; j < 5; ++j) l[t * 5 + j] = o[j];
    }
    __syncthreads();
  }
  if (t < 5) nn[t] = (u32)l[t];
  __syncthreads();
  if (t < 64) {
    int lane = t;
    u32 sidx = scal[0], jstar = scal[1];
    const float* mt = pnorm + (size_t)sidx * DD;
    float mtv[6];
#pragma unroll
    for (int r = 0; r < 6; ++r) mtv[r] = mt[lane + 64 * r];
    float dist[6];
    for (int n = 0; n < 6; ++n) {
      u32 idx = (n == 0) ? jstar : nn[n - 1];
      const float* v = lib + (size_t)idx * DD;
      float p = 0.f;
#pragma unroll
      for (int r = 0; r < 6; ++r) {
        float d = mtv[r] - v[lane + 64 * r];
        p += d * d;
      }
#pragma unroll
      for (int m = 1; m < 64; m <<= 1) p += __shfl_xor(p, m, 64);
      dist[n] = sqrtf(p);
    }
    if (lane == 0) {
      float nrm = dist[0];  // ||m_test_star - m_star|| == s_star (fp32)
      float den = 0.f;
      for (int n = 1; n < 6; ++n) den += expf(dist[n]);
      out[0] = (1.f - expf(nrm) / den) * nrm;
    }
  }
}

// ---- K6: bilinear resize 26x26 -> 224x224 (half-pixel, clamped) ----
__global__ void k_resize(const float* __restrict__ mv, float* __restrict__ A) {
  int i = blockIdx.x * 256 + threadIdx.x;
  int Y = i / IMG, X = i - Y * IMG;
  const float sc = 26.f / 224.f;
  float sy = (Y + 0.5f) * sc - 0.5f;
  float sx = (X + 0.5f) * sc - 0.5f;
  float fy = sy - floorf(sy), fx = sx - floorf(sx);
  int y0 = (int)floorf(sy), x0 = (int)floorf(sx);
  int y1 = y0 + 1, x1 = x0 + 1;
  y0 = min(max(y0, 0), 25); y1 = min(max(y1, 0), 25);
  x0 = min(max(x0, 0), 25); x1 = min(max(x1, 0), 25);
  float v00 = mv[y0 * 26 + x0], v01 = mv[y0 * 26 + x1];
  float v10 = mv[y1 * 26 + x0], v11 = mv[y1 * 26 + x1];
  A[i] = (1.f - fy) * ((1.f - fx) * v00 + fx * v01) + fy * ((1.f - fx) * v10 + fx * v11);
}

// ---- K7/K8: separable 33-tap Gaussian (sigma=4), reflect padding ----
__global__ void k_blurh(const float* __restrict__ A, float* __restrict__ B) {
  __shared__ float kw[33];
  __shared__ float kinv;
  int t = threadIdx.x;
  if (t < 33) {
    float x = ((float)t - 16.f) * 0.25f;
    kw[t] = expf(-0.5f * x * x);
  }
  __syncthreads();
  if (t == 0) {
    float s = 0.f;
    for (int j = 0; j < 33; ++j) s += kw[j];
    kinv = 1.f / s;
  }
  __syncthreads();
  int i = blockIdx.x * 256 + t;
  int Y = i / IMG, X = i - Y * IMG;
  float s = 0.f;
  for (int j = 0; j < 33; ++j) {
    int xx = X + j - 16;
    xx = xx < 0 ? -xx : (xx > 223 ? 446 - xx : xx);
    s += kw[j] * A[Y * IMG + xx];
  }
  B[i] = s * kinv;
}

__global__ void k_blurv(const float* __restrict__ B, float* __restrict__ out) {
  __shared__ float kw[33];
  __shared__ float kinv;
  int t = threadIdx.x;
  if (t < 33) {
    float x = ((float)t - 16.f) * 0.25f;
    kw[t] = expf(-0.5f * x * x);
  }
  __syncthreads();
  if (t == 0) {
    float s = 0.f;
    for (int j = 0; j < 33; ++j) s += kw[j];
    kinv = 1.f / s;
  }
  __syncthreads();
  int i = blockIdx.x * 256 + t;
  int Y = i / IMG, X = i - Y * IMG;
  float s = 0.f;
  for (int j = 0; j < 33; ++j) {
    int yy = Y + j - 16;
    yy = yy < 0 ? -yy : (yy > 223 ? 446 - yy : yy);
    s += kw[j] * B[yy * IMG + X];
  }
  out[1 + i] = s * kinv;  // out[0] = s scalar, map follows
}

extern "C" void kernel_launch(void* const* d_in, const int* in_sizes, int n_in,
                              void* d_out, int out_size, void* d_ws, size_t ws_size,
                              hipStream_t stream) {
  const float* patch = (const float*)d_in[0];   // [676, 384]
  const float* lib   = (const float*)d_in[1];   // [200000, 384]
  float* out = (float*)d_out;                   // [1 + 224*224]
  char* w = (char*)d_ws;

  u64*  packed_ = (u64*)(w + WS_PACKED);
  u32*  scal    = (u32*)(w + WS_SCAL);
  float* mv     = (float*)(w + WS_MV);
  u64*  tops    = (u64*)(w + WS_TOPS);
  float* pnorm  = (float*)(w + WS_PNORM);
  unsigned short* pnb  = (unsigned short*)(w + WS_PNB);
  u64*  dstar   = (u64*)(w + WS_DSTAR);
  float* bufA   = (float*)(w + WS_BUFA);
  float* bufB   = (float*)(w + WS_BUFB);
  unsigned short* libh = (unsigned short*)(w + WS_LIBH);

  k_norm  <<<NPAD, 128, 0, stream>>>(patch, pnorm, pnb, packed_);
  k_conv  <<<2048, 256, 0, stream>>>(lib, libh);
  k_pass1 <<<2346, 256, 0, stream>>>(pnb, libh, packed_);
  k_select<<<1,    256, 0, stream>>>(packed_, scal, mv);
  k_dstar <<<800,  256, 0, stream>>>(libh, scal, dstar);
  k_top5a <<<128,  256, 0, stream>>>(dstar, tops);
  k_final <<<1,    256, 0, stream>>>(tops, scal, pnorm, lib, out);
  k_resize<<<196,  256, 0, stream>>>(mv, bufA);
  k_blurh <<<196,  256, 0, stream>>>(bufA, bufB);
  k_blurv <<<196,  256, 0, stream>>>(bufB, out);
}

// Round 3
// 604.702 us; speedup vs baseline: 1.0866x; 1.0866x over previous
//
#include <hip/hip_runtime.h>
#include <stdint.h>

#define NP    676
#define NPAD  768
#define DD    384
#define MM    200000
#define IMG   224

typedef unsigned int u32;
typedef unsigned long long u64;
typedef short bf16x8 __attribute__((ext_vector_type(8)));
typedef float f32x4 __attribute__((ext_vector_type(4)));

// ---- workspace layout (bytes) ----
#define WS_PACKED   0u         // u64[768]   max-dot keys per row
#define WS_SCAL     6144u      // u32 s_idx, u32 j_star, f32 s_star
#define WS_MV       6400u      // f32[768]   min_val per row
#define WS_TOPS     9728u      // u64[128*5] per-block top5 of d_star
#define WS_PNORM    15360u     // f32[768*384] normalized patch
#define WS_PNB      1195008u   // ushort[768*384] bf16 normalized patch
#define WS_DSTAR    1784832u   // u64[200000] packed (dist,idx)
#define WS_BUFA     3384832u   // f32[50176] resized map
#define WS_BUFB     3585536u   // f32[50176] h-blurred map
#define WS_LIBH     3786240u   // ushort[200000*384] bf16 lib (153.6 MB)

__device__ inline unsigned short f2bf(float f) {
  u32 u = __float_as_uint(f);
  u += 0x7FFFu + ((u >> 16) & 1u);
  return (unsigned short)(u >> 16);
}
__device__ inline float bflo(u32 u) { return __uint_as_float(u << 16); }
__device__ inline float bfhi(u32 u) { return __uint_as_float(u & 0xFFFF0000u); }

// async global->LDS, 16 B per lane: per-lane global src, wave-uniform LDS dst + lane*16
__device__ __forceinline__ void gld16(const void* g, void* l) {
  __builtin_amdgcn_global_load_lds((const __attribute__((address_space(1))) u32*)g,
                                   (__attribute__((address_space(3))) u32*)l, 16, 0, 0);
}

// ---- K1: L2-normalize patch rows, write fp32 + bf16, pad rows to 768.
// Also zero-inits packed_[768] (fused former k_init; blocks 0..5 cover it).
__global__ void k_norm(const float* __restrict__ patch, float* __restrict__ pnorm,
                       unsigned short* __restrict__ pnb, u64* __restrict__ packed_) {
  __shared__ float red[2];
  __shared__ float scs;
  int i = blockIdx.x, t = threadIdx.x;
  if (i < 6) packed_[i * 128 + t] = 0ull;
  if (i >= NP) {
    for (int j = 0; j < 3; ++j) {
      pnorm[(size_t)i * DD + t + 128 * j] = 0.f;
      pnb[(size_t)i * DD + t + 128 * j] = 0;
    }
    return;
  }
  float x0 = patch[(size_t)i * DD + t];
  float x1 = patch[(size_t)i * DD + t + 128];
  float x2 = patch[(size_t)i * DD + t + 256];
  float s = x0 * x0 + x1 * x1 + x2 * x2;
#pragma unroll
  for (int m = 1; m < 64; m <<= 1) s += __shfl_xor(s, m, 64);
  if ((t & 63) == 0) red[t >> 6] = s;
  __syncthreads();
  if (t == 0) scs = 1.f / fmaxf(sqrtf(red[0] + red[1]), 1e-12f);
  __syncthreads();
  float k = scs;
  pnorm[(size_t)i * DD + t]       = x0 * k;
  pnorm[(size_t)i * DD + t + 128] = x1 * k;
  pnorm[(size_t)i * DD + t + 256] = x2 * k;
  pnb[(size_t)i * DD + t]       = f2bf(x0 * k);
  pnb[(size_t)i * DD + t + 128] = f2bf(x1 * k);
  pnb[(size_t)i * DD + t + 256] = f2bf(x2 * k);
}

// ---- K1b: one-time lib fp32 -> bf16 (bf16 lib fits in L3) ----
__global__ void k_conv(const float* __restrict__ lib, unsigned short* __restrict__ libh) {
  const size_t n4 = (size_t)MM * DD / 8;   // output uint4 units (8 bf16)
  const size_t stride = (size_t)gridDim.x * 256;
  const float4* src = (const float4*)lib;
  uint4* dst = (uint4*)libh;
  for (size_t i = (size_t)blockIdx.x * 256 + threadIdx.x; i < n4; i += stride) {
    float4 f0 = src[2 * i], f1 = src[2 * i + 1];
    uint4 o;
    o.x = (u32)f2bf(f0.x) | ((u32)f2bf(f0.y) << 16);
    o.y = (u32)f2bf(f0.z) | ((u32)f2bf(f0.w) << 16);
    o.z = (u32)f2bf(f1.x) | ((u32)f2bf(f1.y) << 16);
    o.w = (u32)f2bf(f1.z) | ((u32)f2bf(f1.w) << 16);
    dst[i] = o;
  }
}

// ---- K2: main pass. 782 col-chunks x 6 row-groups of 128 rows; bijective XCD swizzle
// puts all 6 row-groups of a col-panel on ONE XCD (panel fetched once, L2-served 6x).
// Wave tile = 32 rows: areg[2][12] = 96 regs + ~110 VGPR fits 256-reg budget -> 2
// blocks/CU (2 waves/SIMD latency hiding) with ZERO spill. Round-2 counters proved the
// 64-row tile can have only one of {no-spill, 2-occupancy}; 1 wave/SIMD left every
// ds_read/barrier latency exposed (51.6K cyc/block vs ~4K MFMA busy).
// B streamed via global_load_lds into 4 LDS buffers of 16 cols, depth-3 in flight,
// counted vmcnt(6) + raw s_barrier (no drains). B-frags hoisted to bfr[12] per chunk.
__global__ __launch_bounds__(256, 2) void k_pass1(const unsigned short* __restrict__ pnb,
                                                  const unsigned short* __restrict__ libh,
                                                  u64* __restrict__ packed_) {
  __shared__ __align__(16) unsigned short bt[4 * 6144];   // 4 bufs x 12288 B = 49152 B
  const int t = threadIdx.x;
  // bijective XCD swizzle: 4692 = 8*586 + 4 (xcd 0..3 get 587, 4..7 get 586)
  const int xcd = blockIdx.x & 7;
  const int idx = blockIdx.x >> 3;
  const int logical = (xcd < 4 ? xcd * 587 : 4 * 587 + (xcd - 4) * 586) + idx;
  const int cc = logical / 6, rg = logical - cc * 6;
  const int col0 = cc * 256;
  const int rowbase = rg * 128;
  const int wave = t >> 6, lane = t & 63;
  const int quad = lane >> 4, l15 = lane & 15;
  const int nchunk = (MM - col0 < 256) ? (MM - col0) / 16 : 16;

  // per-lane staging source offsets: slot s=(wave*3+it)*64+lane -> (r=s/48, u=s%48),
  // source unit = u ^ (r&7) so linear LDS write realizes the swizzled layout
  u32 soff[3];
#pragma unroll
  for (int it = 0; it < 3; ++it) {
    int slot = (wave * 3 + it) * 64 + lane;
    int r = slot / 48, u = slot - r * 48;
    soff[it] = (u32)(r * 768 + ((u ^ (r & 7)) << 4));
  }
  // per-lane fragment read byte-offsets within a 12288-B tile (row l15, unit quad+4kt)
  int bo[12];
#pragma unroll
  for (int kt = 0; kt < 12; ++kt)
    bo[kt] = l15 * 768 + (((quad + kt * 4) ^ (l15 & 7)) << 4);

  // ---- A prologue: round q stages 16-row pieces (q*4+j)->buf j; waves (w>>1)==q read
  // pieces 2w,2w+1 from bufs (w&1)*2 + {0,1}
  bf16x8 areg[2][12];
#pragma unroll
  for (int q = 0; q < 2; ++q) {
    if (q) __syncthreads();                 // prev round's reads done before overwrite
#pragma unroll
    for (int j = 0; j < 4; ++j) {
      const char* srcb = (const char*)pnb + (size_t)(rowbase + (q * 4 + j) * 16) * 768;
#pragma unroll
      for (int it = 0; it < 3; ++it)
        gld16(srcb + soff[it], (char*)bt + j * 12288 + (wave * 3 + it) * 1024);
    }
    __syncthreads();                        // full vmcnt drain -> staged data visible
    if ((wave >> 1) == q) {
#pragma unroll
      for (int mi = 0; mi < 2; ++mi)
#pragma unroll
        for (int kt = 0; kt < 12; ++kt)
          areg[mi][kt] = *(const bf16x8*)((const char*)bt +
                                          ((wave & 1) * 2 + mi) * 12288 + bo[kt]);
    }
  }
  __syncthreads();                          // all A-frag reads done before B staging

  u32 best[8];
#pragma unroll
  for (int j = 0; j < 8; ++j) best[j] = 0u;

  const char* bsrc = (const char*)libh + (size_t)col0 * 768;
  // pipeline prologue: stage chunks 0..2 into bufs 0..2 (9 gl_lds outstanding per wave)
#pragma unroll
  for (int pc = 0; pc < 3; ++pc) {
#pragma unroll
    for (int it = 0; it < 3; ++it)
      gld16(bsrc + (size_t)pc * 12288 + soff[it],
            (char*)bt + pc * 12288 + (wave * 3 + it) * 1024);
  }

#pragma unroll 1
  for (int c = 0; c < nchunk; ++c) {
    // wait only for chunk c (3 loads/wave/chunk; keep c+1,c+2 in flight)
    if (c + 3 <= nchunk)      asm volatile("s_waitcnt vmcnt(6)" ::: "memory");
    else if (c + 2 == nchunk) asm volatile("s_waitcnt vmcnt(3)" ::: "memory");
    else                      asm volatile("s_waitcnt vmcnt(0)" ::: "memory");
    __builtin_amdgcn_s_barrier();           // also fences buf (c+3)&3 vs compute(c-1)
    __builtin_amdgcn_sched_barrier(0);
    if (c + 3 < nchunk) {
      const int nb = (c + 3) & 3;
#pragma unroll
      for (int it = 0; it < 3; ++it)
        gld16(bsrc + (size_t)(c + 3) * 12288 + soff[it],
              (char*)bt + nb * 12288 + (wave * 3 + it) * 1024);
    }
    const char* bufb = (const char*)bt + (c & 3) * 12288;
    // hoist all 12 B-frag ds_reads before the MFMA block (one latency, not twelve)
    bf16x8 bfr[12];
#pragma unroll
    for (int kt = 0; kt < 12; ++kt) bfr[kt] = *(const bf16x8*)(bufb + bo[kt]);
    f32x4 acc[2];
#pragma unroll
    for (int mi = 0; mi < 2; ++mi) {
      acc[mi][0] = 0.f; acc[mi][1] = 0.f; acc[mi][2] = 0.f; acc[mi][3] = 0.f;
    }
#pragma unroll
    for (int kt = 0; kt < 12; ++kt) {
#pragma unroll
      for (int mi = 0; mi < 2; ++mi)
        acc[mi] = __builtin_amdgcn_mfma_f32_16x16x32_bf16(areg[mi][kt], bfr[kt], acc[mi], 0, 0, 0);
    }
    // fold: biased key = bits(dot+3)[31:8] | (255 - col_in_wg)  (smaller col wins ties)
    const u32 colbits = 255u - (u32)(c * 16 + l15);
#pragma unroll
    for (int mi = 0; mi < 2; ++mi)
#pragma unroll
      for (int r = 0; r < 4; ++r) {
        u32 kb = __float_as_uint(acc[mi][r] + 3.0f);
        u32 k = (kb & 0xFFFFFF00u) | colbits;
        if (k > best[mi * 4 + r]) best[mi * 4 + r] = k;
      }
  }

  // ---- epilogue: butterfly over the 16 col-lanes, then one global atomic/row
#pragma unroll
  for (int mi = 0; mi < 2; ++mi)
#pragma unroll
    for (int r = 0; r < 4; ++r) {
      u32 k = best[mi * 4 + r];
#pragma unroll
      for (int m = 1; m < 16; m <<= 1) {
        u32 o = (u32)__shfl_xor((int)k, m, 64);
        k = o > k ? o : k;
      }
      if (l15 == 0) {
        int col = col0 + 255 - (int)(k & 255u);
        int row = rowbase + wave * 32 + mi * 16 + quad * 4 + r;
        u64 g = ((u64)(k & 0xFFFFFF00u) << 32) | (u64)(0xFFFFFFFFu - (u32)col);
        atomicMax(&packed_[row], g);
      }
    }
}

// ---- K3: min_val[i], s_idx = argmax(min_val) (first-index tie), j_star ----
__global__ void k_select(const u64* __restrict__ packed_, u32* __restrict__ scal,
                         float* __restrict__ mv) {
  __shared__ u64 red[256];
  int t = threadIdx.x;
  u64 best = 0ull;
  for (int i = t; i < NP; i += 256) {
    u64 p = packed_[i];
    float d = __uint_as_float((u32)(p >> 32)) - 3.0f;   // un-bias
    float dist = sqrtf(fmaxf(2.f - 2.f * d, 0.f));
    mv[i] = dist;
    u64 key = ((u64)__float_as_uint(dist) << 32) | (u32)(0xFFFFFFFFu - (u32)i);
    if (key > best) best = key;
  }
  red[t] = best;
  __syncthreads();
  for (int s = 128; s > 0; s >>= 1) {
    if (t < s && red[t + s] > red[t]) red[t] = red[t + s];
    __syncthreads();
  }
  if (t == 0) {
    u64 k = red[0];
    u32 sidx = 0xFFFFFFFFu - (u32)k;
    u64 p = packed_[sidx];
    u32 jstar = 0xFFFFFFFFu - (u32)p;
    scal[0] = sidx;
    scal[1] = jstar;
    ((float*)scal)[2] = __uint_as_float((u32)(k >> 32));
  }
}

// ---- K4: d_star from bf16 lib (selection only); 4 rows/wave via 16-lane groups
__global__ void k_dstar(const unsigned short* __restrict__ libh, const u32* __restrict__ scal,
                        u64* __restrict__ dstar) {
  int gid = blockIdx.x * 256 + threadIdx.x;
  int w = gid >> 6, lane = gid & 63;
  int quad = lane >> 4, l15 = lane & 15;
  u32 jstar = scal[1];
  const uint4* ms = (const uint4*)(libh + (size_t)jstar * DD);   // 48 uint4/row
  float mf[24];
#pragma unroll
  for (int j = 0; j < 3; ++j) {
    uint4 u = ms[j * 16 + l15];
    mf[j * 8 + 0] = bflo(u.x); mf[j * 8 + 1] = bfhi(u.x);
    mf[j * 8 + 2] = bflo(u.y); mf[j * 8 + 3] = bfhi(u.y);
    mf[j * 8 + 4] = bflo(u.z); mf[j * 8 + 5] = bfhi(u.z);
    mf[j * 8 + 6] = bflo(u.w); mf[j * 8 + 7] = bfhi(u.w);
  }
  for (int r4 = w; r4 < 50000; r4 += 3200) {
    int row = r4 * 4 + quad;
    const uint4* xr = (const uint4*)(libh + (size_t)row * DD);
    float dot = 0.f;
#pragma unroll
    for (int j = 0; j < 3; ++j) {
      uint4 u = xr[j * 16 + l15];
      dot += mf[j * 8 + 0] * bflo(u.x) + mf[j * 8 + 1] * bfhi(u.x);
      dot += mf[j * 8 + 2] * bflo(u.y) + mf[j * 8 + 3] * bfhi(u.y);
      dot += mf[j * 8 + 4] * bflo(u.z) + mf[j * 8 + 5] * bfhi(u.z);
      dot += mf[j * 8 + 6] * bflo(u.w) + mf[j * 8 + 7] * bfhi(u.w);
    }
#pragma unroll
    for (int mm = 1; mm < 16; mm <<= 1) dot += __shfl_xor(dot, mm, 64);
    if (l15 == 0) {
      float dist = sqrtf(fmaxf(2.f - 2.f * dot, 0.f));
      dstar[row] = ((u64)__float_as_uint(dist) << 32) | (u32)row;
    }
  }
}

__device__ inline void merge5(const u64* a, const u64* b, u64* o) {
  int ia = 0, ib = 0;
#pragma unroll
  for (int j = 0; j < 5; ++j) {
    u64 va = a[ia], vb = b[ib];
    if (va <= vb) { o[j] = va; ++ia; } else { o[j] = vb; ++ib; }
  }
}

// ---- K5a: per-block top-5 smallest of d_star ----
__global__ void k_top5a(const u64* __restrict__ dstar, u64* __restrict__ tops) {
  __shared__ u64 l[256 * 5];
  int t = threadIdx.x, b = blockIdx.x;
  int start = b * 1563;
  int end = start + 1563; if (end > MM) end = MM;
  u64 a0 = ~0ull, a1 = ~0ull, a2 = ~0ull, a3 = ~0ull, a4 = ~0ull;
  for (int i = start + t; i < end; i += 256) {
    u64 v = dstar[i];
    if (v < a4) {
      if (v < a0)      { a4 = a3; a3 = a2; a2 = a1; a1 = a0; a0 = v; }
      else if (v < a1) { a4 = a3; a3 = a2; a2 = a1; a1 = v; }
      else if (v < a2) { a4 = a3; a3 = a2; a2 = v; }
      else if (v < a3) { a4 = a3; a3 = v; }
      else             { a4 = v; }
    }
  }
  l[t * 5 + 0] = a0; l[t * 5 + 1] = a1; l[t * 5 + 2] = a2; l[t * 5 + 3] = a3; l[t * 5 + 4] = a4;
  __syncthreads();
  for (int s = 128; s > 0; s >>= 1) {
    if (t < s) {
      u64 o[5];
      merge5(&l[t * 5], &l[(t + s) * 5], o);
#pragma unroll
      for (int j = 0; j < 5; ++j) l[t * 5 + j] = o[j];
    }
    __syncthreads();
  }
  if (t < 5) tops[b * 5 + t] = l[t];
}

// ---- K5b: global top-5 merge + final scalar s (exact fp32 via lib/pnorm) ----
__global__ void k_final(const u64* __restrict__ tops, const u32* __restrict__ scal,
                        const float* __restrict__ pnorm, const float* __restrict__ lib,
                        float* __restrict__ out) {
  __shared__ u64 l[128 * 5];
  __shared__ u32 nn[5];
  int t = threadIdx.x;
  if (t < 128) {
#pragma unroll
    for (int j = 0; j < 5; ++j) l[t * 5 + j] = tops[t * 5 + j];
  }
  __syncthreads();
  for (int s = 64; s > 0; s >>= 1) {
    if (t < s) {
      u64 o[5];
      merge5(&l[t * 5], &l[(t + s) * 5], o);
#pragma unroll
      for (int j = 0; j < 5; ++j) l[t * 5 + j] = o[j];
    }
    __syncthreads();
  }
  if (t < 5) nn[t] = (u32)l[t];
  __syncthreads();
  if (t < 64) {
    int lane = t;
    u32 sidx = scal[0], jstar = scal[1];
    const float* mt = pnorm + (size_t)sidx * DD;
    float mtv[6];
#pragma unroll
    for (int r = 0; r < 6; ++r) mtv[r] = mt[lane + 64 * r];
    float dist[6];
    for (int n = 0; n < 6; ++n) {
      u32 idx = (n == 0) ? jstar : nn[n - 1];
      const float* v = lib + (size_t)idx * DD;
      float p = 0.f;
#pragma unroll
      for (int r = 0; r < 6; ++r) {
        float d = mtv[r] - v[lane + 64 * r];
        p += d * d;
      }
#pragma unroll
      for (int m = 1; m < 64; m <<= 1) p += __shfl_xor(p, m, 64);
      dist[n] = sqrtf(p);
    }
    if (lane == 0) {
      float nrm = dist[0];  // ||m_test_star - m_star|| == s_star (fp32)
      float den = 0.f;
      for (int n = 1; n < 6; ++n) den += expf(dist[n]);
      out[0] = (1.f - expf(nrm) / den) * nrm;
    }
  }
}

// ---- K6: bilinear resize 26x26 -> 224x224 (half-pixel, clamped) ----
__global__ void k_resize(const float* __restrict__ mv, float* __restrict__ A) {
  int i = blockIdx.x * 256 + threadIdx.x;
  int Y = i / IMG, X = i - Y * IMG;
  const float sc = 26.f / 224.f;
  float sy = (Y + 0.5f) * sc - 0.5f;
  float sx = (X + 0.5f) * sc - 0.5f;
  float fy = sy - floorf(sy), fx = sx - floorf(sx);
  int y0 = (int)floorf(sy), x0 = (int)floorf(sx);
  int y1 = y0 + 1, x1 = x0 + 1;
  y0 = min(max(y0, 0), 25); y1 = min(max(y1, 0), 25);
  x0 = min(max(x0, 0), 25); x1 = min(max(x1, 0), 25);
  float v00 = mv[y0 * 26 + x0], v01 = mv[y0 * 26 + x1];
  float v10 = mv[y1 * 26 + x0], v11 = mv[y1 * 26 + x1];
  A[i] = (1.f - fy) * ((1.f - fx) * v00 + fx * v01) + fy * ((1.f - fx) * v10 + fx * v11);
}

// ---- K7/K8: separable 33-tap Gaussian (sigma=4), reflect padding ----
__global__ void k_blurh(const float* __restrict__ A, float* __restrict__ B) {
  __shared__ float kw[33];
  __shared__ float kinv;
  int t = threadIdx.x;
  if (t < 33) {
    float x = ((float)t - 16.f) * 0.25f;
    kw[t] = expf(-0.5f * x * x);
  }
  __syncthreads();
  if (t == 0) {
    float s = 0.f;
    for (int j = 0; j < 33; ++j) s += kw[j];
    kinv = 1.f / s;
  }
  __syncthreads();
  int i = blockIdx.x * 256 + t;
  int Y = i / IMG, X = i - Y * IMG;
  float s = 0.f;
  for (int j = 0; j < 33; ++j) {
    int xx = X + j - 16;
    xx = xx < 0 ? -xx : (xx > 223 ? 446 - xx : xx);
    s += kw[j] * A[Y * IMG + xx];
  }
  B[i] = s * kinv;
}

__global__ void k_blurv(const float* __restrict__ B, float* __restrict__ out) {
  __shared__ float kw[33];
  __shared__ float kinv;
  int t = threadIdx.x;
  if (t < 33) {
    float x = ((float)t - 16.f) * 0.25f;
    kw[t] = expf(-0.5f * x * x);
  }
  __syncthreads();
  if (t == 0) {
    float s = 0.f;
    for (int j = 0; j < 33; ++j) s += kw[j];
    kinv = 1.f / s;
  }
  __syncthreads();
  int i = blockIdx.x * 256 + t;
  int Y = i / IMG, X = i - Y * IMG;
  float s = 0.f;
  for (int j = 0; j < 33; ++j) {
    int yy = Y + j - 16;
    yy = yy < 0 ? -yy : (yy > 223 ? 446 - yy : yy);
    s += kw[j] * B[yy * IMG + X];
  }
  out[1 + i] = s * kinv;  // out[0] = s scalar, map follows
}

extern "C" void kernel_launch(void* const* d_in, const int* in_sizes, int n_in,
                              void* d_out, int out_size, void* d_ws, size_t ws_size,
                              hipStream_t stream) {
  const float* patch = (const float*)d_in[0];   // [676, 384]
  const float* lib   = (const float*)d_in[1];   // [200000, 384]
  float* out = (float*)d_out;                   // [1 + 224*224]
  char* w = (char*)d_ws;

  u64*  packed_ = (u64*)(w + WS_PACKED);
  u32*  scal    = (u32*)(w + WS_SCAL);
  float* mv     = (float*)(w + WS_MV);
  u64*  tops    = (u64*)(w + WS_TOPS);
  float* pnorm  = (float*)(w + WS_PNORM);
  unsigned short* pnb  = (unsigned short*)(w + WS_PNB);
  u64*  dstar   = (u64*)(w + WS_DSTAR);
  float* bufA   = (float*)(w + WS_BUFA);
  float* bufB   = (float*)(w + WS_BUFB);
  unsigned short* libh = (unsigned short*)(w + WS_LIBH);

  k_norm  <<<NPAD, 128, 0, stream>>>(patch, pnorm, pnb, packed_);
  k_conv  <<<2048, 256, 0, stream>>>(lib, libh);
  k_pass1 <<<4692, 256, 0, stream>>>(pnb, libh, packed_);
  k_select<<<1,    256, 0, stream>>>(packed_, scal, mv);
  k_dstar <<<800,  256, 0, stream>>>(libh, scal, dstar);
  k_top5a <<<128,  256, 0, stream>>>(dstar, tops);
  k_final <<<1,    256, 0, stream>>>(tops, scal, pnorm, lib, out);
  k_resize<<<196,  256, 0, stream>>>(mv, bufA);
  k_blurh <<<196,  256, 0, stream>>>(bufA, bufB);
  k_blurv <<<196,  256, 0, stream>>>(bufB, out);
}

// Round 4
// 586.395 us; speedup vs baseline: 1.1205x; 1.0312x over previous
//
#include <hip/hip_runtime.h>
#include <stdint.h>

#define NP    676
#define NPAD  768
#define DD    384
#define MM    200000
#define IMG   224

typedef unsigned int u32;
typedef unsigned long long u64;
typedef short bf16x8 __attribute__((ext_vector_type(8)));
typedef float f32x4 __attribute__((ext_vector_type(4)));

// ---- workspace layout (bytes) ----
#define WS_PACKED   0u         // u64[768]   max-dot keys per row
#define WS_SCAL     6144u      // u32 s_idx, u32 j_star, f32 s_star
#define WS_MV       6400u      // f32[768]   min_val per row
#define WS_TOPS     9728u      // u64[128*5] per-block top5 of d_star
#define WS_PNORM    15360u     // f32[768*384] normalized patch
#define WS_PNB      1195008u   // ushort[768*384] bf16 normalized patch
#define WS_DSTAR    1784832u   // u64[200000] packed (dist,idx)
#define WS_BUFA     3384832u   // f32[50176] resized map
#define WS_BUFB     3585536u   // f32[50176] h-blurred map

__device__ inline unsigned short f2bf(float f) {
  u32 u = __float_as_uint(f);
  u += 0x7FFFu + ((u >> 16) & 1u);
  return (unsigned short)(u >> 16);
}

// packed fp32x2 -> bf16x2 with round-to-nearest-even (bit-identical to f2bf)
__device__ __forceinline__ u32 cvtpk(float lo, float hi) {
  u32 r;
  asm("v_cvt_pk_bf16_f32 %0, %1, %2" : "=v"(r) : "v"(lo), "v"(hi));
  return r;
}

// async global->LDS, 16 B per lane: per-lane global src, wave-uniform LDS dst + lane*16
__device__ __forceinline__ void gld16(const void* g, void* l) {
  __builtin_amdgcn_global_load_lds((const __attribute__((address_space(1))) u32*)g,
                                   (__attribute__((address_space(3))) u32*)l, 16, 0, 0);
}

// ---- K1: L2-normalize patch rows, write fp32 + bf16, pad rows to 768.
// Also zero-inits packed_[768] (blocks 0..5).
__global__ void k_norm(const float* __restrict__ patch, float* __restrict__ pnorm,
                       unsigned short* __restrict__ pnb, u64* __restrict__ packed_) {
  __shared__ float red[2];
  __shared__ float scs;
  int i = blockIdx.x, t = threadIdx.x;
  if (i < 6) packed_[i * 128 + t] = 0ull;
  if (i >= NP) {
    for (int j = 0; j < 3; ++j) {
      pnorm[(size_t)i * DD + t + 128 * j] = 0.f;
      pnb[(size_t)i * DD + t + 128 * j] = 0;
    }
    return;
  }
  float x0 = patch[(size_t)i * DD + t];
  float x1 = patch[(size_t)i * DD + t + 128];
  float x2 = patch[(size_t)i * DD + t + 256];
  float s = x0 * x0 + x1 * x1 + x2 * x2;
#pragma unroll
  for (int m = 1; m < 64; m <<= 1) s += __shfl_xor(s, m, 64);
  if ((t & 63) == 0) red[t >> 6] = s;
  __syncthreads();
  if (t == 0) scs = 1.f / fmaxf(sqrtf(red[0] + red[1]), 1e-12f);
  __syncthreads();
  float k = scs;
  pnorm[(size_t)i * DD + t]       = x0 * k;
  pnorm[(size_t)i * DD + t + 128] = x1 * k;
  pnorm[(size_t)i * DD + t + 256] = x2 * k;
  pnb[(size_t)i * DD + t]       = f2bf(x0 * k);
  pnb[(size_t)i * DD + t + 128] = f2bf(x1 * k);
  pnb[(size_t)i * DD + t + 256] = f2bf(x2 * k);
}

// ---- K2: main pass (k_conv fused in). 782 col-panels x 6 row-groups of 128 rows;
// bijective XCD swizzle puts all 6 row-groups of a panel on ONE XCD.
// Wave tile = 32 rows (areg[2][12] = 96 AGPR, 2 blocks/CU, zero spill — R3-proven).
// B staging: per 16-col chunk each thread loads 96 B of FP32 lib (6 dwordx4),
// converts via v_cvt_pk_bf16_f32 (RNE == f2bf), ds_write_b128 into the XOR-swizzled
// layout. Double-buffered LDS (2 x 12288 B); prefetch chunk c+2 issued before compute
// of chunk c (~600 cyc cover). This removes the separate 77-us k_conv roofline pass.
__global__ __launch_bounds__(256, 2) void k_pass1(const unsigned short* __restrict__ pnb,
                                                  const float* __restrict__ lib,
                                                  u64* __restrict__ packed_) {
  __shared__ __align__(16) unsigned short bt[2 * 6144];   // 2 bufs x 12288 B = 24576 B
  const int t = threadIdx.x;
  // bijective XCD swizzle: 4692 = 8*586 + 4 (xcd 0..3 get 587, 4..7 get 586)
  const int xcd = blockIdx.x & 7;
  const int idx = blockIdx.x >> 3;
  const int logical = (xcd < 4 ? xcd * 587 : 4 * 587 + (xcd - 4) * 586) + idx;
  const int cc = logical / 6, rg = logical - cc * 6;
  const int col0 = cc * 256;
  const int rowbase = rg * 128;
  const int wave = t >> 6, lane = t & 63;
  const int quad = lane >> 4, l15 = lane & 15;
  const int nchunk = (MM - col0 < 256) ? (MM - col0) / 16 : 16;

  // B staging geometry: chunk = 16 cols x 768 B bf16 = 768 16B-units; 3 slots/thread.
  // slot s = it*256+t -> (r = s/48, u = s%48); fp32 src = r*1536 + u*32;
  // ds_write dst = r*768 + ((u^(r&7))<<4)  (source-unit U lives at lds-unit U^(r&7))
  u32 srcoff[3], wdst[3];
#pragma unroll
  for (int it = 0; it < 3; ++it) {
    int s = it * 256 + t;
    int r = s / 48, u = s - r * 48;
    srcoff[it] = (u32)(r * 1536 + u * 32);
    wdst[it]   = (u32)(r * 768 + ((u ^ (r & 7)) << 4));
  }
  // fragment read byte-offsets (row l15, source-unit quad+4kt)
  int bo[12];
#pragma unroll
  for (int kt = 0; kt < 12; ++kt)
    bo[kt] = l15 * 768 + (((quad + 4 * kt) ^ (l15 & 7)) << 4);

  // ---- A prologue: 4 rounds; round q stages rows q*32..q*32+31 (24 KB, 6 gld16/thread,
  // linear LDS dst + pre-swizzled src); wave q reads its 24 fragments.
  bf16x8 areg[2][12];
  {
    u32 soffA[6];
#pragma unroll
    for (int it = 0; it < 6; ++it) {
      int s = (wave * 6 + it) * 64 + lane;
      int r = s / 48, u = s - r * 48;
      soffA[it] = (u32)(r * 768 + ((u ^ (r & 7)) << 4));
    }
#pragma unroll
    for (int q = 0; q < 4; ++q) {
      if (q) __syncthreads();               // prev round's reads done before overwrite
      const char* srcb = (const char*)pnb + (size_t)(rowbase + q * 32) * 768;
#pragma unroll
      for (int it = 0; it < 6; ++it)
        gld16(srcb + soffA[it], (char*)bt + (wave * 6 + it) * 1024);
      __syncthreads();                      // drains vmcnt -> staged data visible
      if (wave == q) {
#pragma unroll
        for (int mi = 0; mi < 2; ++mi)
#pragma unroll
          for (int kt = 0; kt < 12; ++kt)
            areg[mi][kt] = *(const bf16x8*)((const char*)bt +
                            (size_t)(mi * 16 + l15) * 768 +
                            (((quad + 4 * kt) ^ (l15 & 7)) << 4));
      }
    }
  }
  __syncthreads();                          // all A-frag reads done before B staging

  u32 best[8];
#pragma unroll
  for (int j = 0; j < 8; ++j) best[j] = 0u;

  const char* bsrc = (const char*)lib + (size_t)col0 * 1536;   // fp32 panel base
  float4 preg[3][2];

  // ---- B prologue: stage chunk 0 into buf0; issue chunk 1 loads into preg
  {
#pragma unroll
    for (int it = 0; it < 3; ++it) {
      preg[it][0] = *(const float4*)(bsrc + srcoff[it]);
      preg[it][1] = *(const float4*)(bsrc + srcoff[it] + 16);
    }
#pragma unroll
    for (int it = 0; it < 3; ++it) {
      uint4 o;
      o.x = cvtpk(preg[it][0].x, preg[it][0].y);
      o.y = cvtpk(preg[it][0].z, preg[it][0].w);
      o.z = cvtpk(preg[it][1].x, preg[it][1].y);
      o.w = cvtpk(preg[it][1].z, preg[it][1].w);
      *(uint4*)((char*)bt + wdst[it]) = o;
    }
    if (nchunk > 1) {
      const char* s1 = bsrc + 24576;
#pragma unroll
      for (int it = 0; it < 3; ++it) {
        preg[it][0] = *(const float4*)(s1 + srcoff[it]);
        preg[it][1] = *(const float4*)(s1 + srcoff[it] + 16);
      }
    }
  }

  int cur = 0;
#pragma unroll 1
  for (int c = 0; c < nchunk; ++c) {
    __syncthreads();                        // buf[cur] writes visible; buf[cur^1] reads done
    if (c + 1 < nchunk) {
      // convert + write chunk c+1 (preg loaded last iter; compiler waits vmcnt)
#pragma unroll
      for (int it = 0; it < 3; ++it) {
        uint4 o;
        o.x = cvtpk(preg[it][0].x, preg[it][0].y);
        o.y = cvtpk(preg[it][0].z, preg[it][0].w);
        o.z = cvtpk(preg[it][1].x, preg[it][1].y);
        o.w = cvtpk(preg[it][1].z, preg[it][1].w);
        *(uint4*)((char*)bt + (cur ^ 1) * 12288 + wdst[it]) = o;
      }
    }
    if (c + 2 < nchunk) {
      // issue prefetch of chunk c+2 (covered by this chunk's compute)
      const char* s2 = bsrc + (size_t)(c + 2) * 24576;
#pragma unroll
      for (int it = 0; it < 3; ++it) {
        preg[it][0] = *(const float4*)(s2 + srcoff[it]);
        preg[it][1] = *(const float4*)(s2 + srcoff[it] + 16);
      }
    }
    const char* bufb = (const char*)bt + cur * 12288;
    f32x4 acc[2];
#pragma unroll
    for (int mi = 0; mi < 2; ++mi) {
      acc[mi][0] = 0.f; acc[mi][1] = 0.f; acc[mi][2] = 0.f; acc[mi][3] = 0.f;
    }
#pragma unroll
    for (int kt = 0; kt < 12; ++kt) {
      bf16x8 bf = *(const bf16x8*)(bufb + bo[kt]);
#pragma unroll
      for (int mi = 0; mi < 2; ++mi)
        acc[mi] = __builtin_amdgcn_mfma_f32_16x16x32_bf16(areg[mi][kt], bf, acc[mi], 0, 0, 0);
    }
    // fold: biased key = bits(dot+3)[31:8] | (255 - col_in_wg)  (smaller col wins ties)
    const u32 colbits = 255u - (u32)(c * 16 + l15);
#pragma unroll
    for (int mi = 0; mi < 2; ++mi)
#pragma unroll
      for (int r = 0; r < 4; ++r) {
        u32 kb = __float_as_uint(acc[mi][r] + 3.0f);
        u32 k = (kb & 0xFFFFFF00u) | colbits;
        if (k > best[mi * 4 + r]) best[mi * 4 + r] = k;
      }
    cur ^= 1;
  }

  // ---- epilogue: butterfly over the 16 col-lanes, then one global atomic/row
#pragma unroll
  for (int mi = 0; mi < 2; ++mi)
#pragma unroll
    for (int r = 0; r < 4; ++r) {
      u32 k = best[mi * 4 + r];
#pragma unroll
      for (int m = 1; m < 16; m <<= 1) {
        u32 o = (u32)__shfl_xor((int)k, m, 64);
        k = o > k ? o : k;
      }
      if (l15 == 0) {
        int col = col0 + 255 - (int)(k & 255u);
        int row = rowbase + wave * 32 + mi * 16 + quad * 4 + r;
        u64 g = ((u64)(k & 0xFFFFFF00u) << 32) | (u64)(0xFFFFFFFFu - (u32)col);
        atomicMax(&packed_[row], g);
      }
    }
}

// ---- K3: min_val[i], s_idx = argmax(min_val) (first-index tie), j_star ----
__global__ void k_select(const u64* __restrict__ packed_, u32* __restrict__ scal,
                         float* __restrict__ mv) {
  __shared__ u64 red[256];
  int t = threadIdx.x;
  u64 best = 0ull;
  for (int i = t; i < NP; i += 256) {
    u64 p = packed_[i];
    float d = __uint_as_float((u32)(p >> 32)) - 3.0f;   // un-bias
    float dist = sqrtf(fmaxf(2.f - 2.f * d, 0.f));
    mv[i] = dist;
    u64 key = ((u64)__float_as_uint(dist) << 32) | (u32)(0xFFFFFFFFu - (u32)i);
    if (key > best) best = key;
  }
  red[t] = best;
  __syncthreads();
  for (int s = 128; s > 0; s >>= 1) {
    if (t < s && red[t + s] > red[t]) red[t] = red[t + s];
    __syncthreads();
  }
  if (t == 0) {
    u64 k = red[0];
    u32 sidx = 0xFFFFFFFFu - (u32)k;
    u64 p = packed_[sidx];
    u32 jstar = 0xFFFFFFFFu - (u32)p;
    scal[0] = sidx;
    scal[1] = jstar;
    ((float*)scal)[2] = __uint_as_float((u32)(k >> 32));
  }
}

// ---- K4: d_star from FP32 lib (selection only, now exact); 4 rows/wave ----
__global__ void k_dstar(const float* __restrict__ lib, const u32* __restrict__ scal,
                        u64* __restrict__ dstar) {
  int gid = blockIdx.x * 256 + threadIdx.x;
  int w = gid >> 6, lane = gid & 63;
  int quad = lane >> 4, l15 = lane & 15;
  u32 jstar = scal[1];
  const float4* ms = (const float4*)(lib + (size_t)jstar * DD);   // 96 float4/row
  float4 mf[6];
#pragma unroll
  for (int j = 0; j < 6; ++j) mf[j] = ms[j * 16 + l15];
  for (int r4 = w; r4 < 50000; r4 += 3200) {
    int row = r4 * 4 + quad;
    const float4* xr = (const float4*)(lib + (size_t)row * DD);
    float dot = 0.f;
#pragma unroll
    for (int j = 0; j < 6; ++j) {
      float4 u = xr[j * 16 + l15];
      dot += mf[j].x * u.x + mf[j].y * u.y + mf[j].z * u.z + mf[j].w * u.w;
    }
#pragma unroll
    for (int mm = 1; mm < 16; mm <<= 1) dot += __shfl_xor(dot, mm, 64);
    if (l15 == 0) {
      float dist = sqrtf(fmaxf(2.f - 2.f * dot, 0.f));
      dstar[row] = ((u64)__float_as_uint(dist) << 32) | (u32)row;
    }
  }
}

__device__ inline void merge5(const u64* a, const u64* b, u64* o) {
  int ia = 0, ib = 0;
#pragma unroll
  for (int j = 0; j < 5; ++j) {
    u64 va = a[ia], vb = b[ib];
    if (va <= vb) { o[j] = va; ++ia; } else { o[j] = vb; ++ib; }
  }
}

// ---- K5a: per-block top-5 smallest of d_star ----
__global__ void k_top5a(const u64* __restrict__ dstar, u64* __restrict__ tops) {
  __shared__ u64 l[256 * 5];
  int t = threadIdx.x, b = blockIdx.x;
  int start = b * 1563;
  int end = start + 1563; if (end > MM) end = MM;
  u64 a0 = ~0ull, a1 = ~0ull, a2 = ~0ull, a3 = ~0ull, a4 = ~0ull;
  for (int i = start + t; i < end; i += 256) {
    u64 v = dstar[i];
    if (v < a4) {
      if (v < a0)      { a4 = a3; a3 = a2; a2 = a1; a1 = a0; a0 = v; }
      else if (v < a1) { a4 = a3; a3 = a2; a2 = a1; a1 = v; }
      else if (v < a2) { a4 = a3; a3 = a2; a2 = v; }
      else if (v < a3) { a4 = a3; a3 = v; }
      else             { a4 = v; }
    }
  }
  l[t * 5 + 0] = a0; l[t * 5 + 1] = a1; l[t * 5 + 2] = a2; l[t * 5 + 3] = a3; l[t * 5 + 4] = a4;
  __syncthreads();
  for (int s = 128; s > 0; s >>= 1) {
    if (t < s) {
      u64 o[5];
      merge5(&l[t * 5], &l[(t + s) * 5], o);
#pragma unroll
      for (int j = 0; j < 5; ++j) l[t * 5 + j] = o[j];
    }
    __syncthreads();
  }
  if (t < 5) tops[b * 5 + t] = l[t];
}

// ---- K5b: global top-5 merge + final scalar s (exact fp32 via lib/pnorm) ----
__global__ void k_final(const u64* __restrict__ tops, const u32* __restrict__ scal,
                        const float* __restrict__ pnorm, const float* __restrict__ lib,
                        float* __restrict__ out) {
  __shared__ u64 l[128 * 5];
  __shared__ u32 nn[5];
  int t = threadIdx.x;
  if (t < 128) {
#pragma unroll
    for (int j = 0; j < 5; ++j) l[t * 5 + j] = tops[t * 5 + j];
  }
  __syncthreads();
  for (int s = 64; s > 0; s >>= 1) {
    if (t < s) {
      u64 o[5];
      merge5(&l[t * 5], &l[(t + s) * 5], o);
#pragma unroll
      for (int j = 0; j < 5; ++j) l[t * 5 + j] = o[j];
    }
    __syncthreads();
  }
  if (t < 5) nn[t] = (u32)l[t];
  __syncthreads();
  if (t < 64) {
    int lane = t;
    u32 sidx = scal[0], jstar = scal[1];
    const float* mt = pnorm + (size_t)sidx * DD;
    float mtv[6];
#pragma unroll
    for (int r = 0; r < 6; ++r) mtv[r] = mt[lane + 64 * r];
    float dist[6];
    for (int n = 0; n < 6; ++n) {
      u32 idx = (n == 0) ? jstar : nn[n - 1];
      const float* v = lib + (size_t)idx * DD;
      float p = 0.f;
#pragma unroll
      for (int r = 0; r < 6; ++r) {
        float d = mtv[r] - v[lane + 64 * r];
        p += d * d;
      }
#pragma unroll
      for (int m = 1; m < 64; m <<= 1) p += __shfl_xor(p, m, 64);
      dist[n] = sqrtf(p);
    }
    if (lane == 0) {
      float nrm = dist[0];  // ||m_test_star - m_star|| == s_star (fp32)
      float den = 0.f;
      for (int n = 1; n < 6; ++n) den += expf(dist[n]);
      out[0] = (1.f - expf(nrm) / den) * nrm;
    }
  }
}

// ---- K6: bilinear resize 26x26 -> 224x224 (half-pixel, clamped) ----
__global__ void k_resize(const float* __restrict__ mv, float* __restrict__ A) {
  int i = blockIdx.x * 256 + threadIdx.x;
  int Y = i / IMG, X = i - Y * IMG;
  const float sc = 26.f / 224.f;
  float sy = (Y + 0.5f) * sc - 0.5f;
  float sx = (X + 0.5f) * sc - 0.5f;
  float fy = sy - floorf(sy), fx = sx - floorf(sx);
  int y0 = (int)floorf(sy), x0 = (int)floorf(sx);
  int y1 = y0 + 1, x1 = x0 + 1;
  y0 = min(max(y0, 0), 25); y1 = min(max(y1, 0), 25);
  x0 = min(max(x0, 0), 25); x1 = min(max(x1, 0), 25);
  float v00 = mv[y0 * 26 + x0], v01 = mv[y0 * 26 + x1];
  float v10 = mv[y1 * 26 + x0], v11 = mv[y1 * 26 + x1];
  A[i] = (1.f - fy) * ((1.f - fx) * v00 + fx * v01) + fy * ((1.f - fx) * v10 + fx * v11);
}

// ---- K7/K8: separable 33-tap Gaussian (sigma=4), reflect padding ----
__global__ void k_blurh(const float* __restrict__ A, float* __restrict__ B) {
  __shared__ float kw[33];
  __shared__ float kinv;
  int t = threadIdx.x;
  if (t < 33) {
    float x = ((float)t - 16.f) * 0.25f;
    kw[t] = expf(-0.5f * x * x);
  }
  __syncthreads();
  if (t == 0) {
    float s = 0.f;
    for (int j = 0; j < 33; ++j) s += kw[j];
    kinv = 1.f / s;
  }
  __syncthreads();
  int i = blockIdx.x * 256 + t;
  int Y = i / IMG, X = i - Y * IMG;
  float s = 0.f;
  for (int j = 0; j < 33; ++j) {
    int xx = X + j - 16;
    xx = xx < 0 ? -xx : (xx > 223 ? 446 - xx : xx);
    s += kw[j] * A[Y * IMG + xx];
  }
  B[i] = s * kinv;
}

__global__ void k_blurv(const float* __restrict__ B, float* __restrict__ out) {
  __shared__ float kw[33];
  __shared__ float kinv;
  int t = threadIdx.x;
  if (t < 33) {
    float x = ((float)t - 16.f) * 0.25f;
    kw[t] = expf(-0.5f * x * x);
  }
  __syncthreads();
  if (t == 0) {
    float s = 0.f;
    for (int j = 0; j < 33; ++j) s += kw[j];
    kinv = 1.f / s;
  }
  __syncthreads();
  int i = blockIdx.x * 256 + t;
  int Y = i / IMG, X = i - Y * IMG;
  float s = 0.f;
  for (int j = 0; j < 33; ++j) {
    int yy = Y + j - 16;
    yy = yy < 0 ? -yy : (yy > 223 ? 446 - yy : yy);
    s += kw[j] * B[yy * IMG + X];
  }
  out[1 + i] = s * kinv;  // out[0] = s scalar, map follows
}

extern "C" void kernel_launch(void* const* d_in, const int* in_sizes, int n_in,
                              void* d_out, int out_size, void* d_ws, size_t ws_size,
                              hipStream_t stream) {
  const float* patch = (const float*)d_in[0];   // [676, 384]
  const float* lib   = (const float*)d_in[1];   // [200000, 384]
  float* out = (float*)d_out;                   // [1 + 224*224]
  char* w = (char*)d_ws;

  u64*  packed_ = (u64*)(w + WS_PACKED);
  u32*  scal    = (u32*)(w + WS_SCAL);
  float* mv     = (float*)(w + WS_MV);
  u64*  tops    = (u64*)(w + WS_TOPS);
  float* pnorm  = (float*)(w + WS_PNORM);
  unsigned short* pnb  = (unsigned short*)(w + WS_PNB);
  u64*  dstar   = (u64*)(w + WS_DSTAR);
  float* bufA   = (float*)(w + WS_BUFA);
  float* bufB   = (float*)(w + WS_BUFB);

  k_norm  <<<NPAD, 128, 0, stream>>>(patch, pnorm, pnb, packed_);
  k_pass1 <<<4692, 256, 0, stream>>>(pnb, lib, packed_);
  k_select<<<1,    256, 0, stream>>>(packed_, scal, mv);
  k_dstar <<<800,  256, 0, stream>>>(lib, scal, dstar);
  k_top5a <<<128,  256, 0, stream>>>(dstar, tops);
  k_final <<<1,    256, 0, stream>>>(tops, scal, pnorm, lib, out);
  k_resize<<<196,  256, 0, stream>>>(mv, bufA);
  k_blurh <<<196,  256, 0, stream>>>(bufA, bufB);
  k_blurv <<<196,  256, 0, stream>>>(bufB, out);
}